// Round 5
// baseline (39.282 us; speedup 1.0000x reference)
//
#include <hip/hip_runtime.h>
#include <math.h>

#define BB 16
#define TT 1024
#define T1 1025
#define DD 512

__device__ __forceinline__ float fract_exact(float x) {
#if defined(__has_builtin)
#if __has_builtin(__builtin_amdgcn_fractf)
    return __builtin_amdgcn_fractf(x);     // v_fract_f32: x - floor(x), exact
#else
    return x - floorf(x);
#endif
#else
    return x - floorf(x);
#endif
}

// ---------------- Kernel 1: alphas = sigmoid(hidden @ w + b) ----------------
// one 64-lane wave per (b,t) row; 4 waves per 256-thread block
__global__ __launch_bounds__(256) void alpha_kernel(
    const float* __restrict__ hidden,   // [B, T, D]
    const float* __restrict__ w,        // [D]
    const float* __restrict__ bias,     // [1]
    float* __restrict__ alphas_out)     // [B, T1]  (t < T written here)
{
    int row  = blockIdx.x * 4 + (threadIdx.x >> 6);   // 0 .. B*T-1
    int lane = threadIdx.x & 63;
    const float* h = hidden + (size_t)row * DD;
    float4 x0 = *(const float4*)(h + lane * 4);
    float4 x1 = *(const float4*)(h + 256 + lane * 4);
    float4 w0 = *(const float4*)(w + lane * 4);
    float4 w1 = *(const float4*)(w + 256 + lane * 4);
    float s = x0.x * w0.x + x0.y * w0.y + x0.z * w0.z + x0.w * w0.w
            + x1.x * w1.x + x1.y * w1.y + x1.z * w1.z + x1.w * w1.w;
    #pragma unroll
    for (int off = 32; off > 0; off >>= 1) s += __shfl_down(s, off, 64);
    if (lane == 0) {
        float x = s + bias[0];
        float sig = 1.0f / (1.0f + expf(-x));
        int b = row >> 10;       // / TT
        int t = row & 1023;      // % TT
        alphas_out[b * T1 + t] = sig;
    }
}

// ---------------- Kernel 2: sequential CIF scalar scan (per batch) ----------
// 128 threads. Wave0/lane0 runs the minimal serial chain:
//   ni = integrate + a;  peak[t] = ni;  integrate = fract(ni)   (bit-exact)
// 32-step chunks, 4-deep rotating register buffer (#pragma unroll 4 makes the
// rotation static -> zero v_movs; loads issued 128 steps ahead of use).
// Wave1 concurrently computes token_num. Then writeout + ballot compaction.
__global__ __launch_bounds__(128) void scan_kernel(
    float* __restrict__ alphas_out,   // [B, T1]; tail col written here
    float* __restrict__ token_num,    // [B]
    float* __restrict__ cif_peak,     // [B, T1]
    int*   __restrict__ fire_time,    // ws [B, T1]
    int*   __restrict__ nfired)       // ws [B]
{
    int b   = blockIdx.x;
    int tid = threadIdx.x;            // 0..127

    __shared__ float a_sh[TT + 128];  // 4 chunks of zero pad
    __shared__ float peak_sh[T1 + 3];

    // stage alphas (coalesced)
    for (int t = tid; t < TT; t += 128) a_sh[t] = alphas_out[b * T1 + t];
    for (int t = TT + tid; t < TT + 128; t += 128) a_sh[t] = 0.0f;
    __syncthreads();

    if (tid == 0) {
        const float4* a4 = (const float4*)a_sh;
        float4* p4 = (float4*)peak_sh;
        float integrate = 0.0f;

        float4 buf[4][8];             // 4-chunk rotation, 32 steps per chunk
        #pragma unroll
        for (int k = 0; k < 8; ++k) {
            buf[0][k] = a4[k];
            buf[1][k] = a4[8 + k];
            buf[2][k] = a4[16 + k];
            buf[3][k] = a4[24 + k];
        }

        #pragma unroll 4              // c&3 becomes static -> pure renaming
        for (int c = 0; c < 32; ++c) {
            float4 P[8];
            #pragma unroll
            for (int k = 0; k < 8; ++k) {
                float4 A = buf[c & 3][k];
                float n0 = integrate + A.x; P[k].x = n0; float i0 = fract_exact(n0);
                float n1 = i0 + A.y;        P[k].y = n1; float i1 = fract_exact(n1);
                float n2 = i1 + A.z;        P[k].z = n2; float i2 = fract_exact(n2);
                float n3 = i2 + A.w;        P[k].w = n3; integrate = fract_exact(n3);
            }
            #pragma unroll
            for (int k = 0; k < 8; ++k) p4[c * 8 + k] = P[k];
            #pragma unroll
            for (int k = 0; k < 8; ++k) buf[c & 3][k] = a4[(c + 4) * 8 + k]; // pad keeps in-bounds
        }
        // tail step: alpha = 0 -> ni == integrate (< 1, no fire)
        peak_sh[TT] = integrate;
    } else if (tid >= 64) {
        // ---- wave1: token_num = floor(sum alphas), concurrent with chain
        int lane = tid - 64;
        double s = 0.0;
        for (int t = lane; t < TT; t += 64) s += (double)a_sh[t];
        #pragma unroll
        for (int off = 32; off > 0; off >>= 1) s += __shfl_down(s, off, 64);
        if (lane == 0) {
            token_num[b] = (float)floor(s);
            alphas_out[b * T1 + TT] = 0.0f;       // tail column of alphas output
        }
    }
    __syncthreads();

    // coalesced writeout of peaks
    for (int t = tid; t < T1; t += 128) cif_peak[b * T1 + t] = peak_sh[t];

    // fire-time compaction on wave0: fire flag == (peak >= 1.0f)
    if (tid < 64) {
        int cnt = 0;
        int* ft_b = fire_time + b * T1;
        for (int base = 0; base < T1; base += 64) {
            int t = base + tid;
            bool f = (t < T1) && (peak_sh[t] >= 1.0f);
            unsigned long long m = __ballot(f);
            int pos = cnt + __popcll(m & ((1ull << tid) - 1ull));
            if (f) ft_b[pos] = t;
            cnt += __popcll(m);
        }
        if (tid == 0) nfired[b] = cnt;
    }
}

// ---------------- Kernel 3: segmented weighted sums -> packed frames --------
// one block per (b, j) output row; 128 threads x float4 = 512 floats.
// cur/rem reconstructed exactly from (peak, alpha):
//   integrate_prev(t) = peak[t-1] >= 1 ? peak[t-1]-1 : peak[t-1]   (exact)
//   cur(fire t)       = 1 - integrate_prev(t)
//   interior cur(t)   = alpha[t]
//   rem(s)            = alpha[s] - cur(s)
__global__ __launch_bounds__(128) void fill_kernel(
    const float* __restrict__ hidden,     // [B, T, D]
    const float* __restrict__ alphas,     // [B, T1] (output buffer)
    const float* __restrict__ peak,       // [B, T1] (cif_peak output)
    const int*   __restrict__ fire_time,  // ws [B, T1]
    const int*   __restrict__ nfired,     // ws [B]
    float* __restrict__ ae)               // [B, T1, D]
{
    int idx = blockIdx.x;
    int b = idx / T1;
    int j = idx % T1;
    int d = threadIdx.x * 4;
    float4* out4 = (float4*)(ae + ((size_t)b * T1 + j) * DD + d);

    int nf = nfired[b];
    if (j >= nf) {                        // unfired slot: zeros
        *out4 = make_float4(0.f, 0.f, 0.f, 0.f);
        return;
    }
    const int*   ft_b = fire_time + b * T1;
    const float* a_b  = alphas + b * T1;
    const float* pk_b = peak + b * T1;
    const float* hb   = hidden + (size_t)b * TT * DD + d;

    int e = ft_b[j];                      // fire time of this token
    float4 acc = make_float4(0.f, 0.f, 0.f, 0.f);
    int t0;
    if (j > 0) {
        int s = ft_b[j - 1];              // previous fire time
        float ps   = (s > 0) ? pk_b[s - 1] : 0.0f;
        float ips  = (ps >= 1.0f) ? ps - 1.0f : ps;   // integrate before step s
        float curs = 1.0f - ips;                      // dist_completion at s
        float r    = a_b[s] - curs;                   // remainds at s
        float4 h = *(const float4*)(hb + (size_t)s * DD);
        acc.x = r * h.x; acc.y = r * h.y; acc.z = r * h.z; acc.w = r * h.w;
        t0 = s + 1;
    } else {
        t0 = 0;
    }
    for (int t = t0; t < e; ++t) {        // interior rows: cur = alpha
        float c = a_b[t];
        float4 h = *(const float4*)(hb + (size_t)t * DD);
        acc.x += c * h.x; acc.y += c * h.y; acc.z += c * h.z; acc.w += c * h.w;
    }
    {   // final row t = e (the fire): cur = 1 - integrate_prev(e)
        float pe  = (e > 0) ? pk_b[e - 1] : 0.0f;
        float ipe = (pe >= 1.0f) ? pe - 1.0f : pe;
        float ce  = 1.0f - ipe;
        float4 h = *(const float4*)(hb + (size_t)e * DD);
        acc.x += ce * h.x; acc.y += ce * h.y; acc.z += ce * h.z; acc.w += ce * h.w;
    }
    *out4 = acc;
}

extern "C" void kernel_launch(void* const* d_in, const int* in_sizes, int n_in,
                              void* d_out, int out_size, void* d_ws, size_t ws_size,
                              hipStream_t stream) {
    const float* hidden = (const float*)d_in[0];
    const float* w      = (const float*)d_in[1];
    const float* bias   = (const float*)d_in[2];

    float* out        = (float*)d_out;
    float* ae         = out;                                   // [B,T1,D]
    float* token_num  = out + (size_t)BB * T1 * DD;            // [B]
    float* alphas_out = token_num + BB;                        // [B,T1]
    float* cif_peak   = alphas_out + (size_t)BB * T1;          // [B,T1]

    int* fire_time = (int*)d_ws;                               // [B,T1]
    int* nfired    = fire_time + (size_t)BB * T1;              // [B]

    alpha_kernel<<<(BB * TT) / 4, 256, 0, stream>>>(hidden, w, bias, alphas_out);
    scan_kernel<<<BB, 128, 0, stream>>>(alphas_out, token_num, cif_peak,
                                        fire_time, nfired);
    fill_kernel<<<BB * T1, 128, 0, stream>>>(hidden, alphas_out, cif_peak,
                                             fire_time, nfired, ae);
}